// Round 1
// baseline (682.702 us; speedup 1.0000x reference)
//
#include <hip/hip_runtime.h>
#include <hip/hip_bf16.h>
#include <math.h>

// ECE loss: logits [N=131072, C=1000] fp32, target [N] int32.
// Outputs (fp32, concat): [ece, mean(confidence), mean(accuracy)]  (3 floats)
//
// Memory-bound: 524 MB logits read once. One wave per row, float4 coalesced
// loads, online softmax (1 exp per element), argmax with first-occurrence
// tie-break. Per-block LDS histogram + 47 global atomics per block.

constexpr int N_CLASSES = 1000;
constexpr int NBINS     = 15;
constexpr int BLOCK     = 256;
constexpr int GRID      = 2048;
constexpr int WS_FLOATS = 3 * NBINS + 2;   // counts[15], sum_conf[15], sum_acc[15], conf_tot, acc_tot

__global__ __launch_bounds__(BLOCK) void ece_rows(const float* __restrict__ logits,
                                                  const int*   __restrict__ target,
                                                  float*       __restrict__ ws,
                                                  int nrows) {
    __shared__ float sacc[WS_FLOATS];
    const int t = threadIdx.x;
    if (t < WS_FLOATS) sacc[t] = 0.0f;
    __syncthreads();

    const int lane            = t & 63;
    const int wave            = t >> 6;
    const int waves_per_block = BLOCK / 64;
    const int gw              = blockIdx.x * waves_per_block + wave;
    const int nwaves          = gridDim.x * waves_per_block;

    for (int r = gw; r < nrows; r += nwaves) {
        const float4* rowp = reinterpret_cast<const float4*>(logits + (size_t)r * N_CLASSES);

        float m = -INFINITY;   // running max
        float s = 0.0f;        // running sum of exp(x - m)
        int   idx = 0;         // argmax (first occurrence)

        #pragma unroll
        for (int c = 0; c < 4; ++c) {
            const int e0 = c * 256 + lane * 4;     // first element index of this float4
            if (e0 < N_CLASSES) {                  // chunk 3: only lanes 0..57 (58*4=232, 768+232=1000)
                float4 v = rowp[c * 64 + lane];
                float xs[4] = {v.x, v.y, v.z, v.w};
                #pragma unroll
                for (int j = 0; j < 4; ++j) {
                    float x = xs[j];
                    if (x > m) { s = s * __expf(m - x) + 1.0f; m = x; idx = e0 + j; }
                    else       { s += __expf(x - m); }
                }
            }
        }

        // wave-level butterfly merge of (m, s, idx); tie -> min index
        #pragma unroll
        for (int off = 32; off > 0; off >>= 1) {
            float m2 = __shfl_xor(m, off);
            float s2 = __shfl_xor(s, off);
            int   i2 = __shfl_xor(idx, off);
            float M  = fmaxf(m, m2);
            s = s * __expf(m - M) + s2 * __expf(m2 - M);
            if (m2 > m || (m2 == m && i2 < idx)) idx = i2;
            m = M;
        }

        if (lane == 0) {
            float conf = 1.0f / s;                         // probs[argmax] = exp(m-lse) = 1/sumexp
            float acc  = (idx == target[r]) ? 1.0f : 0.0f;
            int bin = (int)ceilf(conf * (float)NBINS) - 1; // (lower, upper] membership
            bin = bin < 0 ? 0 : (bin > NBINS - 1 ? NBINS - 1 : bin);
            atomicAdd(&sacc[bin],             1.0f);
            atomicAdd(&sacc[NBINS + bin],     conf);
            atomicAdd(&sacc[2 * NBINS + bin], acc);
            atomicAdd(&sacc[3 * NBINS],       conf);
            atomicAdd(&sacc[3 * NBINS + 1],   acc);
        }
    }

    __syncthreads();
    if (t < WS_FLOATS) atomicAdd(&ws[t], sacc[t]);
}

__global__ void ece_finalize(const float* __restrict__ ws,
                             float*       __restrict__ out,
                             float inv_n) {
    const int t = threadIdx.x;
    float per = 0.0f;
    if (t < NBINS) {
        float c  = ws[t];
        float sc = ws[NBINS + t];
        float sa = ws[2 * NBINS + t];
        if (c > 0.0f) {
            float safe = fmaxf(c, 1.0f);
            per = (sc / safe - sa / safe) * (c * inv_n);   // (avg_conf - acc) * prop_in_bin
        }
    }
    #pragma unroll
    for (int off = 32; off > 0; off >>= 1) per += __shfl_xor(per, off);
    if (t == 0) {
        out[0] = per;
        out[1] = ws[3 * NBINS]     * inv_n;
        out[2] = ws[3 * NBINS + 1] * inv_n;
    }
}

extern "C" void kernel_launch(void* const* d_in, const int* in_sizes, int n_in,
                              void* d_out, int out_size, void* d_ws, size_t ws_size,
                              hipStream_t stream) {
    const float* logits = (const float*)d_in[0];
    const int*   target = (const int*)d_in[1];
    float*       ws     = (float*)d_ws;
    float*       out    = (float*)d_out;
    const int nrows = in_sizes[1];

    hipMemsetAsync(ws, 0, WS_FLOATS * sizeof(float), stream);
    ece_rows<<<GRID, BLOCK, 0, stream>>>(logits, target, ws, nrows);
    ece_finalize<<<1, 64, 0, stream>>>(ws, out, 1.0f / (float)nrows);
}

// Round 2
// 667.800 us; speedup vs baseline: 1.0223x; 1.0223x over previous
//
#include <hip/hip_runtime.h>
#include <hip/hip_bf16.h>
#include <math.h>

// ECE loss: logits [N=131072, C=1000] fp32, target [N] int32.
// Outputs (fp32, concat): [ece, mean(confidence), mean(accuracy)]  (3 floats)
//
// HBM-bound: 524 MB logits read once -> floor ~83 us @ 6.3 TB/s.
// One wave per row. Two-phase softmax (wave max, then independent exps) to
// avoid the serial online-rescale chain; next-row loads prefetched so each
// wave keeps 4 KB in flight through the compute tail; targets gathered once
// per wave (lane k holds row k's target, delivered by __shfl).

constexpr int N_CLASSES = 1000;
constexpr int NBINS     = 15;
constexpr int BLOCK     = 256;
constexpr int GRID      = 2048;
constexpr int WS_FLOATS = 3 * NBINS + 2;   // counts[15], sum_conf[15], sum_acc[15], conf_tot, acc_tot

__global__ __launch_bounds__(BLOCK) void ece_rows(const float* __restrict__ logits,
                                                  const int*   __restrict__ target,
                                                  float*       __restrict__ ws,
                                                  int nrows) {
    __shared__ float sacc[WS_FLOATS];
    const int t = threadIdx.x;
    if (t < WS_FLOATS) sacc[t] = 0.0f;
    __syncthreads();

    const int lane   = t & 63;
    const int wave   = t >> 6;
    const int gw     = blockIdx.x * (BLOCK / 64) + wave;
    const int nwaves = gridDim.x * (BLOCK / 64);

    // Per-wave target gather: lane k holds the target of this wave's k-th row.
    // (nrows/nwaves = 16 <= 64, so one lane per row suffices.)
    const int rk     = gw + lane * nwaves;
    const int my_tgt = (rk < nrows) ? target[rk] : -1;

    // chunk-3 clamped float4 index: lanes >= 58 re-read the last vector (masked later)
    int c3 = 192 + lane;
    if (c3 > 249) c3 = 249;

    if (gw >= nrows) { __syncthreads(); if (t < WS_FLOATS) atomicAdd(&ws[t], sacc[t]); return; }

    const float4* rowp = reinterpret_cast<const float4*>(logits + (size_t)gw * N_CLASSES);
    float4 cur0 = rowp[lane];
    float4 cur1 = rowp[64 + lane];
    float4 cur2 = rowp[128 + lane];
    float4 cur3 = rowp[c3];

    int k = 0;
    for (int r = gw; r < nrows; r += nwaves, ++k) {
        // ---- prefetch next row (stays in flight through this row's compute) ----
        float4 nxt0, nxt1, nxt2, nxt3;
        const int rn = r + nwaves;
        const bool have_next = rn < nrows;
        if (have_next) {
            const float4* np = reinterpret_cast<const float4*>(logits + (size_t)rn * N_CLASSES);
            nxt0 = np[lane];
            nxt1 = np[64 + lane];
            nxt2 = np[128 + lane];
            nxt3 = np[c3];
        }

        // ---- phase 1: max (no exp, no serial chain) ----
        float xs[16];
        xs[0]  = cur0.x; xs[1]  = cur0.y; xs[2]  = cur0.z; xs[3]  = cur0.w;
        xs[4]  = cur1.x; xs[5]  = cur1.y; xs[6]  = cur1.z; xs[7]  = cur1.w;
        xs[8]  = cur2.x; xs[9]  = cur2.y; xs[10] = cur2.z; xs[11] = cur2.w;
        xs[12] = cur3.x; xs[13] = cur3.y; xs[14] = cur3.z; xs[15] = cur3.w;
        if (lane >= 58) { xs[12] = xs[13] = xs[14] = xs[15] = -INFINITY; }

        float m = xs[0];
        #pragma unroll
        for (int j = 1; j < 16; ++j) m = fmaxf(m, xs[j]);
        #pragma unroll
        for (int off = 32; off > 0; off >>= 1) m = fmaxf(m, __shfl_xor(m, off));

        // ---- phase 2: independent exps + sum + first-occurrence argmax ----
        float s   = 0.0f;
        int   idx = 0x7fffffff;
        #pragma unroll
        for (int c = 0; c < 4; ++c) {
            #pragma unroll
            for (int j = 0; j < 4; ++j) {
                const int   q = c * 4 + j;
                const float x = xs[q];
                s += __expf(x - m);
                const int e = c * 256 + lane * 4 + j;
                if (x == m && e < idx) idx = e;
            }
        }
        #pragma unroll
        for (int off = 32; off > 0; off >>= 1) {
            s  += __shfl_xor(s, off);
            idx = min(idx, __shfl_xor(idx, off));
        }

        const int tr = __shfl(my_tgt, k);   // this row's target, no global load here

        if (lane == 0) {
            const float conf = 1.0f / s;    // probs[argmax] = exp(m - lse) = 1/sum
            const float acc  = (idx == tr) ? 1.0f : 0.0f;
            int bin = (int)ceilf(conf * (float)NBINS) - 1;  // (lower, upper] membership
            bin = bin < 0 ? 0 : (bin > NBINS - 1 ? NBINS - 1 : bin);
            atomicAdd(&sacc[bin],             1.0f);
            atomicAdd(&sacc[NBINS + bin],     conf);
            atomicAdd(&sacc[2 * NBINS + bin], acc);
            atomicAdd(&sacc[3 * NBINS],       conf);
            atomicAdd(&sacc[3 * NBINS + 1],   acc);
        }

        if (have_next) { cur0 = nxt0; cur1 = nxt1; cur2 = nxt2; cur3 = nxt3; }
    }

    __syncthreads();
    if (t < WS_FLOATS) atomicAdd(&ws[t], sacc[t]);
}

__global__ void ece_finalize(const float* __restrict__ ws,
                             float*       __restrict__ out,
                             float inv_n) {
    const int t = threadIdx.x;
    float per = 0.0f;
    if (t < NBINS) {
        float c  = ws[t];
        float sc = ws[NBINS + t];
        float sa = ws[2 * NBINS + t];
        if (c > 0.0f) {
            float safe = fmaxf(c, 1.0f);
            per = (sc / safe - sa / safe) * (c * inv_n);   // (avg_conf - acc) * prop_in_bin
        }
    }
    #pragma unroll
    for (int off = 32; off > 0; off >>= 1) per += __shfl_xor(per, off);
    if (t == 0) {
        out[0] = per;
        out[1] = ws[3 * NBINS]     * inv_n;
        out[2] = ws[3 * NBINS + 1] * inv_n;
    }
}

extern "C" void kernel_launch(void* const* d_in, const int* in_sizes, int n_in,
                              void* d_out, int out_size, void* d_ws, size_t ws_size,
                              hipStream_t stream) {
    const float* logits = (const float*)d_in[0];
    const int*   target = (const int*)d_in[1];
    float*       ws     = (float*)d_ws;
    float*       out    = (float*)d_out;
    const int nrows = in_sizes[1];

    hipMemsetAsync(ws, 0, WS_FLOATS * sizeof(float), stream);
    ece_rows<<<GRID, BLOCK, 0, stream>>>(logits, target, ws, nrows);
    ece_finalize<<<1, 64, 0, stream>>>(ws, out, 1.0f / (float)nrows);
}